// Round 5
// baseline (1933.578 us; speedup 1.0000x reference)
//
#include <hip/hip_runtime.h>
#include <math.h>

#define BB 4
#define NN 4096
#define DIM 128
#define DE 512
#define NTOK (BB * NN)
#define CH 32               // tokens per chunk / per block
#define NCHUNK (NN / CH)    // 128 chunks per batch
#define NBLK (NTOK / CH)    // 512 blocks

typedef __attribute__((ext_vector_type(8))) short bf16x8;
typedef __attribute__((ext_vector_type(4))) float f32x4;
typedef unsigned short us;
typedef unsigned long long u64;

// ---------- helpers ----------
__device__ inline us f2bf(float f) {
    union { float f; unsigned int u; } v; v.f = f;
    unsigned int r = v.u + 0x7FFF + ((v.u >> 16) & 1);   // RNE
    return (us)(r >> 16);
}
__device__ inline float bf2f(unsigned int h16) {
    union { unsigned int u; float f; } v; v.u = (h16 & 0xFFFFu) << 16;
    return v.f;
}
__device__ inline float gelu_erf(float x) {
    return 0.5f * x * (1.0f + erff(x * 0.70710678118654752f));
}
__device__ inline float sigmoidf(float x) {
    return 1.0f / (1.0f + expf(-x));
}

// =====================================================================
// K0: repack W_se[512x128], W_po[512x128], W_ag[128x512] fp32 -> bf16 in
// MFMA B-fragment-linear order: frag f = ct*n_ks+ks holds, at
// [f*512 + lane*8 + j], W[col=ct*16+(lane&15)][k=ks*32+(lane>>4)*8+j].
// =====================================================================
__global__ __launch_bounds__(256) void k0_pack(
    const float* __restrict__ Wse, const float* __restrict__ Wpo,
    const float* __restrict__ Wag, us* __restrict__ wp)
{
    int gid = blockIdx.x * 256 + threadIdx.x;
    int mat = gid >> 13;            // 8192 threads per matrix
    int r   = gid & 8191;
    int f   = r >> 6;               // frag id 0..127
    int lane = r & 63;
    const float* src = (mat == 0) ? Wse : ((mat == 1) ? Wpo : Wag);
    int K     = (mat == 2) ? DE : DIM;
    int shift = (mat == 2) ? 4 : 2;       // n_ks = K/32
    int ct = f >> shift;
    int ks = f & ((1 << shift) - 1);
    int col = ct * 16 + (lane & 15);
    int k0  = ks * 32 + (lane >> 4) * 8;
    const float* s = &src[(size_t)col * K + k0];
    float4 a = *(const float4*)s;
    float4 b = *(const float4*)(s + 4);
    us o[8] = { f2bf(a.x), f2bf(a.y), f2bf(a.z), f2bf(a.w),
                f2bf(b.x), f2bf(b.y), f2bf(b.z), f2bf(b.w) };
    us* d = wp + (size_t)mat * 65536 + ((size_t)f * 64 + lane) * 8;
    *(ushort4*)d       = *(ushort4*)&o[0];
    *(ushort4*)(d + 4) = *(ushort4*)&o[4];
}

// =====================================================================
// KF: fully fused, single pass per 32-token chunk, decoupled lookback:
//   1. h-GEMM (A-frags straight from xq, B-frags from packed wpo)
//      -> gelu/poly2 -> ht (LDS, never to HBM) + chunk column sums
//   2. publish chunk sums (agent-scope atomics) + release flag
//   3. lookback: spin (acquire) on predecessor flags, sum aggregates
//      -> exclusive prefix in registers (no LDS, no barrier needed)
//   4. in-chunk running cumsum + causal mean in place over ht
//   5. s-GEMM (same A-frags, packed wse) -> sigmoid gate in place
//   6. out-projection o @ W_ag^T + b_ag via MFMA
// Deadlock safety: ticket-ordered blocks (wait only on earlier tickets)
// + __launch_bounds__(256,2) => 2 blocks/CU => all 512 blocks resident.
// LDS: ht 33.3 KB + Ssum 2 KB ~= 35.5 KB.
// =====================================================================
#define OPAD 8
__global__ __launch_bounds__(256, 2) void kf_fused(
    const float* __restrict__ xq,
    const us* __restrict__ wse, const us* __restrict__ wpo,
    const us* __restrict__ wag,
    const float* __restrict__ b_se, const float* __restrict__ b_po,
    const float* __restrict__ b_ag,
    unsigned int* __restrict__ ticket, unsigned int* __restrict__ flags,
    u64* __restrict__ S2, float* __restrict__ out)
{
    __shared__ us ht[CH][DE + OPAD];   // h -> agg -> o (in place)
    __shared__ float Ssum[DE];
    __shared__ int blkS;

    const int tid = threadIdx.x;

    Ssum[tid] = 0.f;
    Ssum[tid + 256] = 0.f;
    if (tid == 0) blkS = (int)atomicAdd(ticket, 1u);
    __syncthreads();

    const int blk = blkS;              // ticket-ordered block id
    const int c = blk & (NCHUNK - 1);
    const int bbase = blk & ~(NCHUNK - 1);   // first block id of this batch
    const size_t t0 = (size_t)blk * CH;

    const int lane = tid & 63, w = tid >> 6;
    const int tg = w & 1, chf = w >> 1;
    const int l15 = lane & 15, q = lane >> 4;

    // A-fragments straight from global xq (fp32 -> bf16)
    bf16x8 af[4];
    {
        const float* xrow = xq + (t0 + tg * 16 + l15) * DIM;
        #pragma unroll
        for (int ks = 0; ks < 4; ++ks) {
            float4 a0 = *(const float4*)&xrow[ks * 32 + q * 8];
            float4 a1 = *(const float4*)&xrow[ks * 32 + q * 8 + 4];
            us t[8] = { f2bf(a0.x), f2bf(a0.y), f2bf(a0.z), f2bf(a0.w),
                        f2bf(a1.x), f2bf(a1.y), f2bf(a1.z), f2bf(a1.w) };
            af[ks] = *(bf16x8*)t;
        }
    }

    // ---- phase 1: h-GEMM -> gelu/poly -> ht + chunk sums ----
    {
        f32x4 accL[8], accH[8];
        #pragma unroll
        for (int i = 0; i < 8; ++i) {
            accL[i] = (f32x4){0.f, 0.f, 0.f, 0.f};
            accH[i] = (f32x4){0.f, 0.f, 0.f, 0.f};
        }
        #pragma unroll
        for (int ks = 0; ks < 4; ++ks) {
            #pragma unroll
            for (int i = 0; i < 8; ++i) {
                int ctL = chf * 8 + i;
                bf16x8 bL = *(const bf16x8*)&wpo[(size_t)((ctL * 4 + ks) * 64 + lane) * 8];
                bf16x8 bH = *(const bf16x8*)&wpo[(size_t)(((ctL + 16) * 4 + ks) * 64 + lane) * 8];
                accL[i] = __builtin_amdgcn_mfma_f32_16x16x32_bf16(af[ks], bL, accL[i], 0, 0, 0);
                accH[i] = __builtin_amdgcn_mfma_f32_16x16x32_bf16(af[ks], bH, accH[i], 0, 0, 0);
            }
        }
        #pragma unroll
        for (int i = 0; i < 8; ++i) {
            int colL = (chf * 8 + i) * 16 + l15;
            int colH = colL + 256;
            float bL = b_po[colL], bH = b_po[colH];
            float sL = 0.f, sH = 0.f;
            #pragma unroll
            for (int r = 0; r < 4; ++r) {
                int tok = tg * 16 + q * 4 + r;
                float g1 = gelu_erf(accL[i][r] + bL);
                float g2 = gelu_erf(accH[i][r] + bH);
                float h2 = g2 * g1;
                ht[tok][colL] = f2bf(g1);
                ht[tok][colH] = f2bf(h2);
                sL += g1; sH += h2;
            }
            sL += __shfl_xor(sL, 16); sL += __shfl_xor(sL, 32);
            sH += __shfl_xor(sH, 16); sH += __shfl_xor(sH, 32);
            if (q == 0) {
                atomicAdd(&Ssum[colL], sL);
                atomicAdd(&Ssum[colH], sH);
            }
        }
    }
    __syncthreads();

    // ---- phase 2: publish chunk sums + flag ----
    {
        int d = tid * 2;
        union { float f[2]; u64 u; } pv;
        pv.f[0] = Ssum[d]; pv.f[1] = Ssum[d + 1];
        __hip_atomic_store(&S2[(size_t)blk * 256 + tid], pv.u,
                           __ATOMIC_RELAXED, __HIP_MEMORY_SCOPE_AGENT);
    }
    __syncthreads();
    if (tid == 0)
        __hip_atomic_store(&flags[blk], 1u,
                           __ATOMIC_RELEASE, __HIP_MEMORY_SCOPE_AGENT);

    // ---- phase 3+4: lookback prefix (registers) + in-chunk cumsum ----
    {
        int d = tid * 2;
        float r0 = 0.f, r1 = 0.f;
        for (int cc = bbase; cc < blk; ++cc) {
            while (__hip_atomic_load(&flags[cc], __ATOMIC_ACQUIRE,
                                     __HIP_MEMORY_SCOPE_AGENT) != 1u) {}
            u64 v = __hip_atomic_load(&S2[(size_t)cc * 256 + tid],
                                      __ATOMIC_RELAXED, __HIP_MEMORY_SCOPE_AGENT);
            union { u64 u; float f[2]; } pv; pv.u = v;
            r0 += pv.f[0]; r1 += pv.f[1];
        }
        // in-chunk running cumsum + causal mean (own columns only -> no barrier)
        #pragma unroll 4
        for (int n = 0; n < CH; ++n) {
            unsigned hv = *(unsigned*)&ht[n][d];
            r0 += bf2f(hv);
            r1 += bf2f(hv >> 16);
            float inv = 1.0f / ((float)(c * CH + n + 1) + 1e-7f);
            *(unsigned*)&ht[n][d] = (unsigned)f2bf(r0 * inv)
                                  | ((unsigned)f2bf(r1 * inv) << 16);
        }
    }
    __syncthreads();

    // ---- phase 5: s-GEMM -> o = sigmoid(s) * agg (in place over ht) ----
    {
        f32x4 accL[8], accH[8];
        #pragma unroll
        for (int i = 0; i < 8; ++i) {
            accL[i] = (f32x4){0.f, 0.f, 0.f, 0.f};
            accH[i] = (f32x4){0.f, 0.f, 0.f, 0.f};
        }
        #pragma unroll
        for (int ks = 0; ks < 4; ++ks) {
            #pragma unroll
            for (int i = 0; i < 8; ++i) {
                int ctL = chf * 8 + i;
                bf16x8 bL = *(const bf16x8*)&wse[(size_t)((ctL * 4 + ks) * 64 + lane) * 8];
                bf16x8 bH = *(const bf16x8*)&wse[(size_t)(((ctL + 16) * 4 + ks) * 64 + lane) * 8];
                accL[i] = __builtin_amdgcn_mfma_f32_16x16x32_bf16(af[ks], bL, accL[i], 0, 0, 0);
                accH[i] = __builtin_amdgcn_mfma_f32_16x16x32_bf16(af[ks], bH, accH[i], 0, 0, 0);
            }
        }
        #pragma unroll
        for (int i = 0; i < 8; ++i) {
            int colL = (chf * 8 + i) * 16 + l15;
            int colH = colL + 256;
            float bL = b_se[colL], bH = b_se[colH];
            #pragma unroll
            for (int r = 0; r < 4; ++r) {
                int tok = tg * 16 + q * 4 + r;
                float aggL = bf2f((unsigned)ht[tok][colL]);
                float aggH = bf2f((unsigned)ht[tok][colH]);
                ht[tok][colL] = f2bf(sigmoidf(accL[i][r] + bL) * aggL);
                ht[tok][colH] = f2bf(sigmoidf(accH[i][r] + bH) * aggH);
            }
        }
    }
    __syncthreads();

    // ---- phase 6: out-projection o @ W_ag^T + b_ag ----
    {
        f32x4 acc[4];
        #pragma unroll
        for (int i = 0; i < 4; ++i) acc[i] = (f32x4){0.f, 0.f, 0.f, 0.f};

        for (int ks = 0; ks < 16; ++ks) {
            bf16x8 a = *(const bf16x8*)&ht[tg * 16 + l15][ks * 32 + q * 8];
            #pragma unroll
            for (int i = 0; i < 4; ++i) {
                int ct = chf * 4 + i;
                bf16x8 bb = *(const bf16x8*)&wag[(size_t)((ct * 16 + ks) * 64 + lane) * 8];
                acc[i] = __builtin_amdgcn_mfma_f32_16x16x32_bf16(a, bb, acc[i], 0, 0, 0);
            }
        }
        #pragma unroll
        for (int i = 0; i < 4; ++i) {
            int col = (chf * 4 + i) * 16 + l15;
            float bv = b_ag[col];
            #pragma unroll
            for (int r = 0; r < 4; ++r) {
                size_t tok = t0 + tg * 16 + q * 4 + r;
                out[tok * DIM + col] = acc[i][r] + bv;
            }
        }
    }
}

extern "C" void kernel_launch(void* const* d_in, const int* in_sizes, int n_in,
                              void* d_out, int out_size, void* d_ws, size_t ws_size,
                              hipStream_t stream)
{
    const float* xq   = (const float*)d_in[0];
    // d_in[1] = mask: causal tril -> replaced by prefix-sum algorithm
    const float* W_se = (const float*)d_in[2];
    const float* b_se = (const float*)d_in[3];
    const float* W_po = (const float*)d_in[4];
    const float* b_po = (const float*)d_in[5];
    const float* W_ag = (const float*)d_in[6];
    const float* b_ag = (const float*)d_in[7];
    float* out = (float*)d_out;

    us* wp  = (us*)d_ws;                 // 3 x 65536 bf16, fragment-packed (384 KB)
    us* wse = wp;
    us* wpo = wp + 65536;
    us* wag = wp + 131072;
    unsigned int* ctrl  = (unsigned int*)(wp + 196608); // ticket + flags
    unsigned int* ticket = ctrl;
    unsigned int* flags  = ctrl + 1;
    u64* S2 = (u64*)((char*)ctrl + 4096);   // [NBLK][256] packed chunk sums (1 MB)

    // zero ticket + flags (graph-capturable memset node)
    hipMemsetAsync(ctrl, 0, 4 + NBLK * 4, stream);
    k0_pack<<<96, 256, 0, stream>>>(W_se, W_po, W_ag, wp);
    kf_fused<<<NBLK, 256, 0, stream>>>(xq, wse, wpo, wag, b_se, b_po, b_ag,
                                       ticket, flags, S2, out);
}

// Round 6
// 357.253 us; speedup vs baseline: 5.4123x; 5.4123x over previous
//
#include <hip/hip_runtime.h>
#include <math.h>

#define BB 4
#define NN 4096
#define DIM 128
#define DE 512
#define NTOK (BB * NN)
#define CH 32               // tokens per chunk / per block
#define NCHUNK (NN / CH)    // 128 chunks per batch
#define NBLK (NTOK / CH)    // 512 blocks

typedef __attribute__((ext_vector_type(8))) short bf16x8;
typedef __attribute__((ext_vector_type(4))) float f32x4;
typedef unsigned short us;

// ---------- helpers ----------
__device__ inline us f2bf(float f) {
    union { float f; unsigned int u; } v; v.f = f;
    unsigned int r = v.u + 0x7FFF + ((v.u >> 16) & 1);   // RNE
    return (us)(r >> 16);
}
__device__ inline float bf2f(unsigned int h16) {
    union { unsigned int u; float f; } v; v.u = (h16 & 0xFFFFu) << 16;
    return v.f;
}
// Branch-free erf, Abramowitz-Stegun 7.1.26, |abs err| <= 1.5e-7
__device__ inline float erf_fast(float x) {
    float ax = fabsf(x);
    float t = 1.0f / (1.0f + 0.3275911f * ax);
    float poly = t * (0.254829592f + t * (-0.284496736f +
                 t * (1.421413741f + t * (-1.453152027f + t * 1.061405429f))));
    float r = 1.0f - poly * __expf(-ax * ax);
    return copysignf(r, x);
}
__device__ inline float gelu_erf(float x) {
    return 0.5f * x * (1.0f + erf_fast(x * 0.70710678118654752f));
}
__device__ inline float sigmoidf(float x) {
    return 1.0f / (1.0f + __expf(-x));
}

// =====================================================================
// K0: repack W_se[512x128], W_po[512x128], W_ag[128x512] fp32 -> bf16 in
// MFMA B-fragment-linear order: frag f = ct*n_ks+ks holds, at
// [f*512 + lane*8 + j], W[col=ct*16+(lane&15)][k=ks*32+(lane>>4)*8+j].
// =====================================================================
__global__ __launch_bounds__(256) void k0_pack(
    const float* __restrict__ Wse, const float* __restrict__ Wpo,
    const float* __restrict__ Wag, us* __restrict__ wp)
{
    int gid = blockIdx.x * 256 + threadIdx.x;
    int mat = gid >> 13;            // 8192 threads per matrix
    int r   = gid & 8191;
    int f   = r >> 6;               // frag id 0..127
    int lane = r & 63;
    const float* src = (mat == 0) ? Wse : ((mat == 1) ? Wpo : Wag);
    int K     = (mat == 2) ? DE : DIM;
    int shift = (mat == 2) ? 4 : 2;       // n_ks = K/32
    int ct = f >> shift;
    int ks = f & ((1 << shift) - 1);
    int col = ct * 16 + (lane & 15);
    int k0  = ks * 32 + (lane >> 4) * 8;
    const float* s = &src[(size_t)col * K + k0];
    float4 a = *(const float4*)s;
    float4 b = *(const float4*)(s + 4);
    us o[8] = { f2bf(a.x), f2bf(a.y), f2bf(a.z), f2bf(a.w),
                f2bf(b.x), f2bf(b.y), f2bf(b.z), f2bf(b.w) };
    us* d = wp + (size_t)mat * 65536 + ((size_t)f * 64 + lane) * 8;
    *(ushort4*)d       = *(ushort4*)&o[0];
    *(ushort4*)(d + 4) = *(ushort4*)&o[4];
}

// =====================================================================
// K1: h-GEMM (xq @ W_po^T + b_po -> gelu -> poly2) via bf16 MFMA.
//   - A-frags loaded directly from xq (no LDS staging)
//   - hp written in fragment-linear layout (coalesced 16B/lane stores)
//   - fused per-chunk column sums -> S [NBLK][DE] fp32
// LDS: Ssum 2 KB only.
// =====================================================================
__global__ __launch_bounds__(256) void k1_hsum(
    const float* __restrict__ xq, const us* __restrict__ wpo,
    const float* __restrict__ b_po, us* __restrict__ hp,
    float* __restrict__ S)
{
    __shared__ float Ssum[DE];

    const int tid = threadIdx.x;
    const int blk = blockIdx.x;
    const size_t t0 = (size_t)blk * CH;

    Ssum[tid] = 0.f;
    Ssum[tid + 256] = 0.f;

    const int lane = tid & 63, w = tid >> 6;
    const int tg = w & 1, chf = w >> 1;
    const int l15 = lane & 15, q = lane >> 4;

    // A-fragments straight from global xq (fp32 -> bf16)
    bf16x8 af[4];
    {
        const float* xrow = xq + (t0 + tg * 16 + l15) * DIM;
        #pragma unroll
        for (int ks = 0; ks < 4; ++ks) {
            float4 a0 = *(const float4*)&xrow[ks * 32 + q * 8];
            float4 a1 = *(const float4*)&xrow[ks * 32 + q * 8 + 4];
            us t[8] = { f2bf(a0.x), f2bf(a0.y), f2bf(a0.z), f2bf(a0.w),
                        f2bf(a1.x), f2bf(a1.y), f2bf(a1.z), f2bf(a1.w) };
            af[ks] = *(bf16x8*)t;
        }
    }

    f32x4 accL[8], accH[8];
    #pragma unroll
    for (int i = 0; i < 8; ++i) {
        accL[i] = (f32x4){0.f, 0.f, 0.f, 0.f};
        accH[i] = (f32x4){0.f, 0.f, 0.f, 0.f};
    }
    #pragma unroll
    for (int ks = 0; ks < 4; ++ks) {
        #pragma unroll
        for (int i = 0; i < 8; ++i) {
            int ctL = chf * 8 + i;
            bf16x8 bL = *(const bf16x8*)&wpo[(size_t)((ctL * 4 + ks) * 64 + lane) * 8];
            bf16x8 bH = *(const bf16x8*)&wpo[(size_t)(((ctL + 16) * 4 + ks) * 64 + lane) * 8];
            accL[i] = __builtin_amdgcn_mfma_f32_16x16x32_bf16(af[ks], bL, accL[i], 0, 0, 0);
            accH[i] = __builtin_amdgcn_mfma_f32_16x16x32_bf16(af[ks], bH, accH[i], 0, 0, 0);
        }
    }

    __syncthreads();   // Ssum init visible before atomics

    #pragma unroll
    for (int i = 0; i < 8; ++i) {
        int colL = (chf * 8 + i) * 16 + l15;
        int colH = colL + 256;
        float bL = b_po[colL], bH = b_po[colH];
        float g1v[4], h2v[4];
        float sL = 0.f, sH = 0.f;
        #pragma unroll
        for (int r = 0; r < 4; ++r) {
            float g1 = gelu_erf(accL[i][r] + bL);
            float g2 = gelu_erf(accH[i][r] + bH);
            g1v[r] = g1;
            h2v[r] = g2 * g1;
            sL += g1;
            sH += h2v[r];
        }
        uint4 st;
        st.x = (unsigned)f2bf(g1v[0]) | ((unsigned)f2bf(g1v[1]) << 16);
        st.y = (unsigned)f2bf(g1v[2]) | ((unsigned)f2bf(g1v[3]) << 16);
        st.z = (unsigned)f2bf(h2v[0]) | ((unsigned)f2bf(h2v[1]) << 16);
        st.w = (unsigned)f2bf(h2v[2]) | ((unsigned)f2bf(h2v[3]) << 16);
        *(uint4*)&hp[((((size_t)blk * 4 + w) * 8 + i) * 64 + lane) * 8] = st;

        sL += __shfl_xor(sL, 16); sL += __shfl_xor(sL, 32);
        sH += __shfl_xor(sH, 16); sH += __shfl_xor(sH, 32);
        if (q == 0) {
            atomicAdd(&Ssum[colL], sL);
            atomicAdd(&Ssum[colH], sH);
        }
    }
    __syncthreads();
    S[(size_t)blk * DE + tid]       = Ssum[tid];
    S[(size_t)blk * DE + tid + 256] = Ssum[tid + 256];
}

// =====================================================================
// K2s: in-place exclusive scan of chunk sums (128 chunks per batch),
// unrolled x8 so L2 loads pipeline. grid = BB.
// =====================================================================
__global__ __launch_bounds__(256) void k2s_scan(float* __restrict__ S)
{
    const int b = blockIdx.x;
    const int d0 = threadIdx.x * 2;
    float r0 = 0.f, r1 = 0.f;
    for (int g = 0; g < NCHUNK / 8; ++g) {
        float2 v[8];
        #pragma unroll
        for (int j = 0; j < 8; ++j)
            v[j] = *(const float2*)&S[((size_t)b * NCHUNK + g * 8 + j) * DE + d0];
        #pragma unroll
        for (int j = 0; j < 8; ++j) {
            float2 e = { r0, r1 };
            *(float2*)&S[((size_t)b * NCHUNK + g * 8 + j) * DE + d0] = e;
            r0 += v[j].x; r1 += v[j].y;
        }
    }
}

// =====================================================================
// K3: per-chunk fused:
//   - load hp frags (C-layout, coalesced) + stage prefix row -> LDS
//   - s-GEMM (A-frags from xq, packed wse) -> sigmoid -> bf16 regs
//   - register cumsum: lane scan over r, __shfl_up scan over q,
//     LDS exchange for cross-wave (tg) half-chunk totals
//   - causal mean + gate in registers -> single LDS write of o
//   - out-projection o @ W_ag^T + b_ag via MFMA
// LDS: ht 33.3 + pre 2 + halfT 2 = 37.3 KB. 2 barriers.
// =====================================================================
#define OPAD 8
__global__ __launch_bounds__(256) void k3_gate_out(
    const float* __restrict__ xq, const us* __restrict__ hp,
    const us* __restrict__ wse, const us* __restrict__ wag,
    const float* __restrict__ b_se, const float* __restrict__ S,
    const float* __restrict__ b_ag, float* __restrict__ out)
{
    __shared__ us ht[CH][DE + OPAD];
    __shared__ float pre[DE];
    __shared__ float halfT[DE];

    const int tid = threadIdx.x;
    const int blk = blockIdx.x;
    const int c = blk & (NCHUNK - 1);
    const size_t t0 = (size_t)blk * CH;

    const int lane = tid & 63, w = tid >> 6;
    const int tg = w & 1, chf = w >> 1;
    const int l15 = lane & 15, q = lane >> 4;

    // issue hp fragment loads early (coalesced 16B/lane)
    uint4 hv[8];
    #pragma unroll
    for (int i = 0; i < 8; ++i)
        hv[i] = *(const uint4*)&hp[((((size_t)blk * 4 + w) * 8 + i) * 64 + lane) * 8];

    // stage exclusive-prefix row for this chunk into LDS
    {
        float2 p = *(const float2*)&S[(size_t)blk * DE + tid * 2];
        *(float2*)&pre[tid * 2] = p;
    }

    // A-fragments from xq
    bf16x8 af[4];
    {
        const float* xrow = xq + (t0 + tg * 16 + l15) * DIM;
        #pragma unroll
        for (int ks = 0; ks < 4; ++ks) {
            float4 a0 = *(const float4*)&xrow[ks * 32 + q * 8];
            float4 a1 = *(const float4*)&xrow[ks * 32 + q * 8 + 4];
            us t[8] = { f2bf(a0.x), f2bf(a0.y), f2bf(a0.z), f2bf(a0.w),
                        f2bf(a1.x), f2bf(a1.y), f2bf(a1.z), f2bf(a1.w) };
            af[ks] = *(bf16x8*)t;
        }
    }

    // s-GEMM -> sigmoid -> packed bf16 regs
    uint4 sgv[8];
    {
        f32x4 accL[8], accH[8];
        #pragma unroll
        for (int i = 0; i < 8; ++i) {
            accL[i] = (f32x4){0.f, 0.f, 0.f, 0.f};
            accH[i] = (f32x4){0.f, 0.f, 0.f, 0.f};
        }
        #pragma unroll
        for (int ks = 0; ks < 4; ++ks) {
            #pragma unroll
            for (int i = 0; i < 8; ++i) {
                int ctL = chf * 8 + i;
                bf16x8 bL = *(const bf16x8*)&wse[(size_t)((ctL * 4 + ks) * 64 + lane) * 8];
                bf16x8 bH = *(const bf16x8*)&wse[(size_t)(((ctL + 16) * 4 + ks) * 64 + lane) * 8];
                accL[i] = __builtin_amdgcn_mfma_f32_16x16x32_bf16(af[ks], bL, accL[i], 0, 0, 0);
                accH[i] = __builtin_amdgcn_mfma_f32_16x16x32_bf16(af[ks], bH, accH[i], 0, 0, 0);
            }
        }
        #pragma unroll
        for (int i = 0; i < 8; ++i) {
            int colL = (chf * 8 + i) * 16 + l15;
            float bL = b_se[colL], bH = b_se[colL + 256];
            us sl[4], sh[4];
            #pragma unroll
            for (int r = 0; r < 4; ++r) {
                sl[r] = f2bf(sigmoidf(accL[i][r] + bL));
                sh[r] = f2bf(sigmoidf(accH[i][r] + bH));
            }
            sgv[i].x = (unsigned)sl[0] | ((unsigned)sl[1] << 16);
            sgv[i].y = (unsigned)sl[2] | ((unsigned)sl[3] << 16);
            sgv[i].z = (unsigned)sh[0] | ((unsigned)sh[1] << 16);
            sgv[i].w = (unsigned)sh[2] | ((unsigned)sh[3] << 16);
        }
    }

    // register cumsum: lane scan over r, shfl scan over q; publish
    // half-chunk totals (tg=0 waves) for the cross-wave offset.
    float pL[8][4], pH[8][4];        // lane-inclusive partials
    float qexL[8], qexH[8];          // exclusive prefix over q groups
    #pragma unroll
    for (int i = 0; i < 8; ++i) {
        float v0 = bf2f(hv[i].x), v1 = bf2f(hv[i].x >> 16);
        float v2 = bf2f(hv[i].y), v3 = bf2f(hv[i].y >> 16);
        pL[i][0] = v0; pL[i][1] = v0 + v1;
        pL[i][2] = pL[i][1] + v2; pL[i][3] = pL[i][2] + v3;
        float u0 = bf2f(hv[i].z), u1 = bf2f(hv[i].z >> 16);
        float u2 = bf2f(hv[i].w), u3 = bf2f(hv[i].w >> 16);
        pH[i][0] = u0; pH[i][1] = u0 + u1;
        pH[i][2] = pH[i][1] + u2; pH[i][3] = pH[i][2] + u3;

        // inclusive scan of per-q totals across lanes {l15, l15+16, +32, +48}
        float scL = pL[i][3];
        float uu = __shfl_up(scL, 16); scL += (q >= 1) ? uu : 0.f;
        uu = __shfl_up(scL, 32);       scL += (q >= 2) ? uu : 0.f;
        float scH = pH[i][3];
        uu = __shfl_up(scH, 16);       scH += (q >= 1) ? uu : 0.f;
        uu = __shfl_up(scH, 32);       scH += (q >= 2) ? uu : 0.f;
        qexL[i] = scL - pL[i][3];
        qexH[i] = scH - pH[i][3];

        // half-chunk (16-token) totals live at q=3
        float htL = __shfl(scL, l15 + 48);
        float htH = __shfl(scH, l15 + 48);
        if (tg == 0 && q == 0) {
            int colL = (chf * 8 + i) * 16 + l15;
            halfT[colL] = htL;
            halfT[colL + 256] = htH;
        }
    }
    __syncthreads();   // halfT + pre visible

    // causal mean + gate -> o -> LDS ht
    #pragma unroll
    for (int i = 0; i < 8; ++i) {
        int colL = (chf * 8 + i) * 16 + l15;
        int colH = colL + 256;
        float baseL = pre[colL] + qexL[i] + (tg ? halfT[colL] : 0.f);
        float baseH = pre[colH] + qexH[i] + (tg ? halfT[colH] : 0.f);
        unsigned sgp[4] = { sgv[i].x, sgv[i].y, sgv[i].z, sgv[i].w };
        #pragma unroll
        for (int r = 0; r < 4; ++r) {
            int tok = tg * 16 + q * 4 + r;
            float inv = 1.0f / ((float)(c * CH + tok + 1) + 1e-7f);
            float sL = bf2f(r & 1 ? sgp[r >> 1] >> 16 : sgp[r >> 1]);
            float sH = bf2f(r & 1 ? sgp[2 + (r >> 1)] >> 16 : sgp[2 + (r >> 1)]);
            ht[tok][colL] = f2bf(sL * (baseL + pL[i][r]) * inv);
            ht[tok][colH] = f2bf(sH * (baseH + pH[i][r]) * inv);
        }
    }
    __syncthreads();

    // out-projection o @ W_ag^T + b_ag
    {
        f32x4 acc[4];
        #pragma unroll
        for (int i = 0; i < 4; ++i) acc[i] = (f32x4){0.f, 0.f, 0.f, 0.f};

        for (int ks = 0; ks < 16; ++ks) {
            bf16x8 a = *(const bf16x8*)&ht[tg * 16 + l15][ks * 32 + q * 8];
            #pragma unroll
            for (int i = 0; i < 4; ++i) {
                int ct = chf * 4 + i;
                bf16x8 bb = *(const bf16x8*)&wag[(size_t)((ct * 16 + ks) * 64 + lane) * 8];
                acc[i] = __builtin_amdgcn_mfma_f32_16x16x32_bf16(a, bb, acc[i], 0, 0, 0);
            }
        }
        #pragma unroll
        for (int i = 0; i < 4; ++i) {
            int col = (chf * 4 + i) * 16 + l15;
            float bv = b_ag[col];
            #pragma unroll
            for (int r = 0; r < 4; ++r) {
                size_t tok = t0 + tg * 16 + q * 4 + r;
                out[tok * DIM + col] = acc[i][r] + bv;
            }
        }
    }
}

extern "C" void kernel_launch(void* const* d_in, const int* in_sizes, int n_in,
                              void* d_out, int out_size, void* d_ws, size_t ws_size,
                              hipStream_t stream)
{
    const float* xq   = (const float*)d_in[0];
    // d_in[1] = mask: causal tril -> replaced by prefix-sum algorithm
    const float* W_se = (const float*)d_in[2];
    const float* b_se = (const float*)d_in[3];
    const float* W_po = (const float*)d_in[4];
    const float* b_po = (const float*)d_in[5];
    const float* W_ag = (const float*)d_in[6];
    const float* b_ag = (const float*)d_in[7];
    float* out = (float*)d_out;

    us* wp  = (us*)d_ws;               // 3 x 65536 bf16, fragment-packed
    us* wse = wp;
    us* wpo = wp + 65536;
    us* wag = wp + 131072;
    float* S = (float*)(wp + 196608);  // [NBLK][DE] fp32 chunk sums (1 MB)
    us* hp   = (us*)(S + (size_t)NBLK * DE);   // [NTOK*DE] bf16, frag-linear

    k0_pack<<<96, 256, 0, stream>>>(W_se, W_po, W_ag, wp);
    k1_hsum<<<NBLK, 256, 0, stream>>>(xq, wpo, b_po, hp, S);
    k2s_scan<<<BB, 256, 0, stream>>>(S);
    k3_gate_out<<<NBLK, 256, 0, stream>>>(xq, hp, wse, wag, b_se, S, b_ag, out);
}

// Round 8
// 354.571 us; speedup vs baseline: 5.4533x; 1.0076x over previous
//
#include <hip/hip_runtime.h>
#include <math.h>

#define BB 4
#define NN 4096
#define DIM 128
#define DE 512
#define NTOK (BB * NN)
#define CH 32               // tokens per chunk / per block
#define NCHUNK (NN / CH)    // 128 chunks per batch
#define NBLK (NTOK / CH)    // 512 blocks

typedef __attribute__((ext_vector_type(8))) short bf16x8;
typedef __attribute__((ext_vector_type(4))) float f32x4;
typedef unsigned short us;

// ---------- helpers ----------
__device__ inline us f2bf(float f) {
    union { float f; unsigned int u; } v; v.f = f;
    unsigned int r = v.u + 0x7FFF + ((v.u >> 16) & 1);   // RNE
    return (us)(r >> 16);
}
__device__ inline float bf2f(unsigned int h16) {
    union { unsigned int u; float f; } v; v.u = (h16 & 0xFFFFu) << 16;
    return v.f;
}
// Branch-free erf, Abramowitz-Stegun 7.1.26, |abs err| <= 1.5e-7
__device__ inline float erf_fast(float x) {
    float ax = fabsf(x);
    float t = 1.0f / (1.0f + 0.3275911f * ax);
    float poly = t * (0.254829592f + t * (-0.284496736f +
                 t * (1.421413741f + t * (-1.453152027f + t * 1.061405429f))));
    float r = 1.0f - poly * __expf(-ax * ax);
    return copysignf(r, x);
}
__device__ inline float gelu_erf(float x) {
    return 0.5f * x * (1.0f + erf_fast(x * 0.70710678118654752f));
}
__device__ inline float sigmoidf(float x) {
    return 1.0f / (1.0f + __expf(-x));
}

// =====================================================================
// K0: repack W_se[512x128], W_po[512x128], W_ag[128x512] fp32 -> bf16 in
// MFMA B-fragment-linear order: frag f = ct*n_ks+ks holds, at
// [f*512 + lane*8 + j], W[col=ct*16+(lane&15)][k=ks*32+(lane>>4)*8+j].
// =====================================================================
__global__ __launch_bounds__(256) void k0_pack(
    const float* __restrict__ Wse, const float* __restrict__ Wpo,
    const float* __restrict__ Wag, us* __restrict__ wp)
{
    int gid = blockIdx.x * 256 + threadIdx.x;
    int mat = gid >> 13;            // 8192 threads per matrix
    int r   = gid & 8191;
    int f   = r >> 6;               // frag id 0..127
    int lane = r & 63;
    const float* src = (mat == 0) ? Wse : ((mat == 1) ? Wpo : Wag);
    int K     = (mat == 2) ? DE : DIM;
    int shift = (mat == 2) ? 4 : 2;       // n_ks = K/32
    int ct = f >> shift;
    int ks = f & ((1 << shift) - 1);
    int col = ct * 16 + (lane & 15);
    int k0  = ks * 32 + (lane >> 4) * 8;
    const float* s = &src[(size_t)col * K + k0];
    float4 a = *(const float4*)s;
    float4 b = *(const float4*)(s + 4);
    us o[8] = { f2bf(a.x), f2bf(a.y), f2bf(a.z), f2bf(a.w),
                f2bf(b.x), f2bf(b.y), f2bf(b.z), f2bf(b.w) };
    us* d = wp + (size_t)mat * 65536 + ((size_t)f * 64 + lane) * 8;
    *(ushort4*)d       = *(ushort4*)&o[0];
    *(ushort4*)(d + 4) = *(ushort4*)&o[4];
}

// =====================================================================
// K1: h-GEMM (xq @ W_po^T + b_po -> gelu -> poly2) via bf16 MFMA.
//   - A-frags loaded directly from xq (no LDS staging)
//   - hp written in fragment-linear layout (coalesced 16B/lane stores)
//   - fused per-chunk column sums -> S [NBLK][DE] fp32 (RAW, unscanned)
// LDS: Ssum 2 KB only.
// =====================================================================
__global__ __launch_bounds__(256) void k1_hsum(
    const float* __restrict__ xq, const us* __restrict__ wpo,
    const float* __restrict__ b_po, us* __restrict__ hp,
    float* __restrict__ S)
{
    __shared__ float Ssum[DE];

    const int tid = threadIdx.x;
    const int blk = blockIdx.x;
    const size_t t0 = (size_t)blk * CH;

    Ssum[tid] = 0.f;
    Ssum[tid + 256] = 0.f;

    const int lane = tid & 63, w = tid >> 6;
    const int tg = w & 1, chf = w >> 1;
    const int l15 = lane & 15, q = lane >> 4;

    // A-fragments straight from global xq (fp32 -> bf16)
    bf16x8 af[4];
    {
        const float* xrow = xq + (t0 + tg * 16 + l15) * DIM;
        #pragma unroll
        for (int ks = 0; ks < 4; ++ks) {
            float4 a0 = *(const float4*)&xrow[ks * 32 + q * 8];
            float4 a1 = *(const float4*)&xrow[ks * 32 + q * 8 + 4];
            us t[8] = { f2bf(a0.x), f2bf(a0.y), f2bf(a0.z), f2bf(a0.w),
                        f2bf(a1.x), f2bf(a1.y), f2bf(a1.z), f2bf(a1.w) };
            af[ks] = *(bf16x8*)t;
        }
    }

    f32x4 accL[8], accH[8];
    #pragma unroll
    for (int i = 0; i < 8; ++i) {
        accL[i] = (f32x4){0.f, 0.f, 0.f, 0.f};
        accH[i] = (f32x4){0.f, 0.f, 0.f, 0.f};
    }
    #pragma unroll
    for (int ks = 0; ks < 4; ++ks) {
        #pragma unroll
        for (int i = 0; i < 8; ++i) {
            int ctL = chf * 8 + i;
            bf16x8 bL = *(const bf16x8*)&wpo[(size_t)((ctL * 4 + ks) * 64 + lane) * 8];
            bf16x8 bH = *(const bf16x8*)&wpo[(size_t)(((ctL + 16) * 4 + ks) * 64 + lane) * 8];
            accL[i] = __builtin_amdgcn_mfma_f32_16x16x32_bf16(af[ks], bL, accL[i], 0, 0, 0);
            accH[i] = __builtin_amdgcn_mfma_f32_16x16x32_bf16(af[ks], bH, accH[i], 0, 0, 0);
        }
    }

    __syncthreads();   // Ssum init visible before atomics

    #pragma unroll
    for (int i = 0; i < 8; ++i) {
        int colL = (chf * 8 + i) * 16 + l15;
        int colH = colL + 256;
        float bL = b_po[colL], bH = b_po[colH];
        float g1v[4], h2v[4];
        float sL = 0.f, sH = 0.f;
        #pragma unroll
        for (int r = 0; r < 4; ++r) {
            float g1 = gelu_erf(accL[i][r] + bL);
            float g2 = gelu_erf(accH[i][r] + bH);
            g1v[r] = g1;
            h2v[r] = g2 * g1;
            sL += g1;
            sH += h2v[r];
        }
        uint4 st;
        st.x = (unsigned)f2bf(g1v[0]) | ((unsigned)f2bf(g1v[1]) << 16);
        st.y = (unsigned)f2bf(g1v[2]) | ((unsigned)f2bf(g1v[3]) << 16);
        st.z = (unsigned)f2bf(h2v[0]) | ((unsigned)f2bf(h2v[1]) << 16);
        st.w = (unsigned)f2bf(h2v[2]) | ((unsigned)f2bf(h2v[3]) << 16);
        *(uint4*)&hp[((((size_t)blk * 4 + w) * 8 + i) * 64 + lane) * 8] = st;

        sL += __shfl_xor(sL, 16); sL += __shfl_xor(sL, 32);
        sH += __shfl_xor(sH, 16); sH += __shfl_xor(sH, 32);
        if (q == 0) {
            atomicAdd(&Ssum[colL], sL);
            atomicAdd(&Ssum[colH], sH);
        }
    }
    __syncthreads();
    S[(size_t)blk * DE + tid]       = Ssum[tid];
    S[(size_t)blk * DE + tid + 256] = Ssum[tid + 256];
}

// =====================================================================
// K3: per-chunk fused:
//   - x8-unrolled exclusive prefix over raw S rows [bbase, blk) (L2-hot)
//   - load hp frags (C-layout, coalesced)
//   - s-GEMM (A-frags from xq, packed wse) -> sigmoid -> bf16 regs
//   - register cumsum: lane scan over r, __shfl_up scan over q,
//     LDS exchange for cross-wave half-chunk totals
//   - causal mean + gate in registers -> single LDS write of o
//   - out-projection o @ W_ag^T + b_ag via MFMA
// LDS: ht 33.3 + pre 2 + halfT 2 = 37.3 KB. 2 barriers.
// =====================================================================
#define OPAD 8
__global__ __launch_bounds__(256) void k3_gate_out(
    const float* __restrict__ xq, const us* __restrict__ hp,
    const us* __restrict__ wse, const us* __restrict__ wag,
    const float* __restrict__ b_se, const float* __restrict__ S,
    const float* __restrict__ b_ag, float* __restrict__ out)
{
    __shared__ us ht[CH][DE + OPAD];
    __shared__ float pre[DE];
    __shared__ float halfT[DE];

    const int tid = threadIdx.x;
    const int blk = blockIdx.x;
    const int c = blk & (NCHUNK - 1);
    const int bbase = blk & ~(NCHUNK - 1);
    const size_t t0 = (size_t)blk * CH;

    const int lane = tid & 63, w = tid >> 6;
    const int tg = w & 1, chf = w >> 1;
    const int l15 = lane & 15, q = lane >> 4;

    // issue hp fragment loads early (coalesced 16B/lane)
    uint4 hv[8];
    #pragma unroll
    for (int i = 0; i < 8; ++i)
        hv[i] = *(const uint4*)&hp[((((size_t)blk * 4 + w) * 8 + i) * 64 + lane) * 8];

    // exclusive prefix over raw chunk-sum rows (x8 unrolled, pipelined)
    {
        const int d0 = tid * 2;
        float r0 = 0.f, r1 = 0.f;
        int cc = bbase;
        for (; cc + 8 <= blk; cc += 8) {
            float2 v[8];
            #pragma unroll
            for (int j = 0; j < 8; ++j)
                v[j] = *(const float2*)&S[((size_t)cc + j) * DE + d0];
            #pragma unroll
            for (int j = 0; j < 8; ++j) { r0 += v[j].x; r1 += v[j].y; }
        }
        for (; cc < blk; ++cc) {
            float2 v = *(const float2*)&S[(size_t)cc * DE + d0];
            r0 += v.x; r1 += v.y;
        }
        pre[d0] = r0; pre[d0 + 1] = r1;
    }

    // A-fragments from xq
    bf16x8 af[4];
    {
        const float* xrow = xq + (t0 + tg * 16 + l15) * DIM;
        #pragma unroll
        for (int ks = 0; ks < 4; ++ks) {
            float4 a0 = *(const float4*)&xrow[ks * 32 + q * 8];
            float4 a1 = *(const float4*)&xrow[ks * 32 + q * 8 + 4];
            us t[8] = { f2bf(a0.x), f2bf(a0.y), f2bf(a0.z), f2bf(a0.w),
                        f2bf(a1.x), f2bf(a1.y), f2bf(a1.z), f2bf(a1.w) };
            af[ks] = *(bf16x8*)t;
        }
    }

    // s-GEMM -> sigmoid -> packed bf16 regs
    uint4 sgv[8];
    {
        f32x4 accL[8], accH[8];
        #pragma unroll
        for (int i = 0; i < 8; ++i) {
            accL[i] = (f32x4){0.f, 0.f, 0.f, 0.f};
            accH[i] = (f32x4){0.f, 0.f, 0.f, 0.f};
        }
        #pragma unroll
        for (int ks = 0; ks < 4; ++ks) {
            #pragma unroll
            for (int i = 0; i < 8; ++i) {
                int ctL = chf * 8 + i;
                bf16x8 bL = *(const bf16x8*)&wse[(size_t)((ctL * 4 + ks) * 64 + lane) * 8];
                bf16x8 bH = *(const bf16x8*)&wse[(size_t)(((ctL + 16) * 4 + ks) * 64 + lane) * 8];
                accL[i] = __builtin_amdgcn_mfma_f32_16x16x32_bf16(af[ks], bL, accL[i], 0, 0, 0);
                accH[i] = __builtin_amdgcn_mfma_f32_16x16x32_bf16(af[ks], bH, accH[i], 0, 0, 0);
            }
        }
        #pragma unroll
        for (int i = 0; i < 8; ++i) {
            int colL = (chf * 8 + i) * 16 + l15;
            float bL = b_se[colL], bH = b_se[colL + 256];
            us sl[4], sh[4];
            #pragma unroll
            for (int r = 0; r < 4; ++r) {
                sl[r] = f2bf(sigmoidf(accL[i][r] + bL));
                sh[r] = f2bf(sigmoidf(accH[i][r] + bH));
            }
            sgv[i].x = (unsigned)sl[0] | ((unsigned)sl[1] << 16);
            sgv[i].y = (unsigned)sl[2] | ((unsigned)sl[3] << 16);
            sgv[i].z = (unsigned)sh[0] | ((unsigned)sh[1] << 16);
            sgv[i].w = (unsigned)sh[2] | ((unsigned)sh[3] << 16);
        }
    }

    // register cumsum: lane scan over r, shfl scan over q; publish
    // half-chunk totals (tg=0 waves) for the cross-wave offset.
    float pL[8][4], pH[8][4];        // lane-inclusive partials
    float qexL[8], qexH[8];          // exclusive prefix over q groups
    #pragma unroll
    for (int i = 0; i < 8; ++i) {
        float v0 = bf2f(hv[i].x), v1 = bf2f(hv[i].x >> 16);
        float v2 = bf2f(hv[i].y), v3 = bf2f(hv[i].y >> 16);
        pL[i][0] = v0; pL[i][1] = v0 + v1;
        pL[i][2] = pL[i][1] + v2; pL[i][3] = pL[i][2] + v3;
        float u0 = bf2f(hv[i].z), u1 = bf2f(hv[i].z >> 16);
        float u2 = bf2f(hv[i].w), u3 = bf2f(hv[i].w >> 16);
        pH[i][0] = u0; pH[i][1] = u0 + u1;
        pH[i][2] = pH[i][1] + u2; pH[i][3] = pH[i][2] + u3;

        // inclusive scan of per-q totals across lanes {l15, l15+16, +32, +48}
        float scL = pL[i][3];
        float uu = __shfl_up(scL, 16); scL += (q >= 1) ? uu : 0.f;
        uu = __shfl_up(scL, 32);       scL += (q >= 2) ? uu : 0.f;
        float scH = pH[i][3];
        uu = __shfl_up(scH, 16);       scH += (q >= 1) ? uu : 0.f;
        uu = __shfl_up(scH, 32);       scH += (q >= 2) ? uu : 0.f;
        qexL[i] = scL - pL[i][3];
        qexH[i] = scH - pH[i][3];

        // half-chunk (16-token) totals live at q=3
        float htL = __shfl(scL, l15 + 48);
        float htH = __shfl(scH, l15 + 48);
        if (tg == 0 && q == 0) {
            int colL = (chf * 8 + i) * 16 + l15;
            halfT[colL] = htL;
            halfT[colL + 256] = htH;
        }
    }
    __syncthreads();   // halfT + pre visible

    // causal mean + gate -> o -> LDS ht
    #pragma unroll
    for (int i = 0; i < 8; ++i) {
        int colL = (chf * 8 + i) * 16 + l15;
        int colH = colL + 256;
        float baseL = pre[colL] + qexL[i] + (tg ? halfT[colL] : 0.f);
        float baseH = pre[colH] + qexH[i] + (tg ? halfT[colH] : 0.f);
        unsigned sgp[4] = { sgv[i].x, sgv[i].y, sgv[i].z, sgv[i].w };
        #pragma unroll
        for (int r = 0; r < 4; ++r) {
            int tok = tg * 16 + q * 4 + r;
            float inv = 1.0f / ((float)(c * CH + tok + 1) + 1e-7f);
            float sL = bf2f(r & 1 ? sgp[r >> 1] >> 16 : sgp[r >> 1]);
            float sH = bf2f(r & 1 ? sgp[2 + (r >> 1)] >> 16 : sgp[2 + (r >> 1)]);
            ht[tok][colL] = f2bf(sL * (baseL + pL[i][r]) * inv);
            ht[tok][colH] = f2bf(sH * (baseH + pH[i][r]) * inv);
        }
    }
    __syncthreads();

    // out-projection o @ W_ag^T + b_ag
    {
        f32x4 acc[4];
        #pragma unroll
        for (int i = 0; i < 4; ++i) acc[i] = (f32x4){0.f, 0.f, 0.f, 0.f};

        for (int ks = 0; ks < 16; ++ks) {
            bf16x8 a = *(const bf16x8*)&ht[tg * 16 + l15][ks * 32 + q * 8];
            #pragma unroll
            for (int i = 0; i < 4; ++i) {
                int ct = chf * 4 + i;
                bf16x8 bb = *(const bf16x8*)&wag[(size_t)((ct * 16 + ks) * 64 + lane) * 8];
                acc[i] = __builtin_amdgcn_mfma_f32_16x16x32_bf16(a, bb, acc[i], 0, 0, 0);
            }
        }
        #pragma unroll
        for (int i = 0; i < 4; ++i) {
            int col = (chf * 4 + i) * 16 + l15;
            float bv = b_ag[col];
            #pragma unroll
            for (int r = 0; r < 4; ++r) {
                size_t tok = t0 + tg * 16 + q * 4 + r;
                out[tok * DIM + col] = acc[i][r] + bv;
            }
        }
    }
}

extern "C" void kernel_launch(void* const* d_in, const int* in_sizes, int n_in,
                              void* d_out, int out_size, void* d_ws, size_t ws_size,
                              hipStream_t stream)
{
    const float* xq   = (const float*)d_in[0];
    // d_in[1] = mask: causal tril -> replaced by prefix-sum algorithm
    const float* W_se = (const float*)d_in[2];
    const float* b_se = (const float*)d_in[3];
    const float* W_po = (const float*)d_in[4];
    const float* b_po = (const float*)d_in[5];
    const float* W_ag = (const float*)d_in[6];
    const float* b_ag = (const float*)d_in[7];
    float* out = (float*)d_out;

    us* wp  = (us*)d_ws;               // 3 x 65536 bf16, fragment-packed
    us* wse = wp;
    us* wpo = wp + 65536;
    us* wag = wp + 131072;
    float* S = (float*)(wp + 196608);  // [NBLK][DE] fp32 raw chunk sums (1 MB)
    us* hp   = (us*)(S + (size_t)NBLK * DE);   // [NTOK*DE] bf16, frag-linear

    k0_pack<<<96, 256, 0, stream>>>(W_se, W_po, W_ag, wp);
    k1_hsum<<<NBLK, 256, 0, stream>>>(xq, wpo, b_po, hp, S);
    k3_gate_out<<<NBLK, 256, 0, stream>>>(xq, hp, wse, wag, b_se, S, b_ag, out);
}